// Round 6
// baseline (365.684 us; speedup 1.0000x reference)
//
#include <hip/hip_runtime.h>
#include <stdint.h>

#define D 128
#define Ssz 10
#define HP 136   // LDS row pad (u16) — 272 B row stride, 16B-aligned (mult of 8!)
#define NB 4096  // batch

typedef uint16_t u16;
typedef uint32_t u32;
typedef __attribute__((ext_vector_type(8))) short short8;
typedef __attribute__((ext_vector_type(4))) float f32x4;

#define AS1U32(p) ((const __attribute__((address_space(1))) u32*)(p))
#define AS3U32(p) ((__attribute__((address_space(3))) u32*)(p))

__device__ __forceinline__ u16 f2bf(float f){
  u32 x = __float_as_uint(f);
  return (u16)((x + 0x7fffu + ((x >> 16) & 1u)) >> 16);   // RNE
}
__device__ __forceinline__ float bf2f(u16 u){ return __uint_as_float(((u32)u) << 16); }

// branch-free fast tanh: 1 - 2/(e^{2x}+1); exact at +-inf, abs err ~1e-7
__device__ __forceinline__ float ftanh(float x){
  float e = __expf(2.0f * x);
  return 1.0f - 2.0f / (e + 1.0f);
}

// Fused preamble: all weight transposes + cell cvt in one launch.
__global__ __launch_bounds__(256) void prep_kernel(
    const float* __restrict__ W_drug, const float* __restrict__ W_gene,
    const float* __restrict__ rnn_Wx, const float* __restrict__ rnn_Wh,
    const float* __restrict__ cell_tab,
    u16* __restrict__ WdT, u16* __restrict__ WgT,
    u16* __restrict__ WxT6, u16* __restrict__ WhT6,
    u16* __restrict__ cellT)
{
  int i = blockIdx.x * 256 + threadIdx.x;
  if (i < 131072){
    int n = i >> 10, k = i & 1023;
    WdT[i] = f2bf(W_drug[k * D + n]);
  } else if (i < 393216){
    int j = i - 131072;
    int n = j >> 11, k = j & 2047;
    WgT[j] = f2bf(W_gene[k * D + n]);
  } else if (i < 491520){
    int j = i - 393216;
    int n = (j >> 7) & 127, k = j & 127;
    WxT6[j] = f2bf(rnn_Wx[(j & ~16383) + k * D + n]);
  } else if (i < 589824){
    int j = i - 491520;
    int n = (j >> 7) & 127, k = j & 127;
    WhT6[j] = f2bf(rnn_Wh[(j & ~16383) + k * D + n]);
  } else {
    int j = i - 589824;                 // j < 128000
    float v0 = cell_tab[2 * j], v1 = cell_tab[2 * j + 1];
    ((u32*)cellT)[j] = (u32)f2bf(v0) | ((u32)f2bf(v1) << 16);
  }
}

// DENSE projection + fused per-layer x@Wx epilogue.
// 32-row tiles for occupancy (grid = M/32): wave w owns rows (w&1)*16..+16,
// cols (w>>1)*64..+64. B-chunk staging identical to the proven 64-row kernel.
//   P[m][n]    = feats[m][:K] . WT[n][:K] + bias[n]
//   xw{0,1}[m] = bf16(P[m]) @ Wx{0,1} + rb{0,1}   (f32, for the RNN)
//   outf[m]    = P[m] (f32, optional)
__global__ __launch_bounds__(256, 2) void proj_gemm(
    const float* __restrict__ feats, int K, int M,
    const u16* __restrict__ WT,       // bf16 [128][K]
    const float* __restrict__ bias,   // f32 [128]
    const u16* __restrict__ Wx0,      // bf16 [128][128] n-major (layer 0)
    const u16* __restrict__ Wx1,      // layer 1
    const float* __restrict__ rb0,    // rnn bias [128]
    const float* __restrict__ rb1,
    float* __restrict__ xw0,          // f32 [M][128]
    float* __restrict__ xw1,
    float* __restrict__ outf)         // f32 [M][128] or null
{
  __shared__ u16 Bt[128 * 128];       // B chunk [n][swizzled]; reused as P-tiles

  int lane = threadIdx.x & 63;
  int wave = threadIdx.x >> 6;
  int quad = lane >> 4, l16 = lane & 15;
  int wrow = (wave & 1) * 16;         // row half
  int wcol = (wave >> 1) * 64;        // col half
  int m0 = blockIdx.x * 32;

  int row = min(m0 + wrow + l16, M - 1);
  const float* aptr = feats + (long)row * K + quad * 8;

  int st_nrow = wave * 32 + (lane >> 4);
  int st_p    = lane & 15;

  f32x4 acc[4];
#pragma unroll
  for (int nt = 0; nt < 4; ++nt){
    float bv = bias[wcol + nt * 16 + l16];
    f32x4 t = {bv, bv, bv, bv};
    acc[nt] = t;
  }

  f32x4 afA[4][2], afB[4][2];
#pragma unroll
  for (int ks = 0; ks < 4; ++ks){
    afA[ks][0] = *(const f32x4*)(aptr + ks * 32);
    afA[ks][1] = *(const f32x4*)(aptr + ks * 32 + 4);
  }

  auto chunk_step = [&](f32x4 (&acur)[4][2], f32x4 (&anxt)[4][2], int kc) {
#pragma unroll
    for (int j = 0; j < 8; ++j){
      int n = st_nrow + j * 4;
      int c = st_p ^ (n & 15);
      const u16* g = WT + (long)n * K + kc + c * 8;
      __builtin_amdgcn_global_load_lds(AS1U32(g),
                                       AS3U32(&Bt[(wave * 8 + j) * 512]),
                                       16, 0, 0);
    }
    if (kc + 128 < K){
#pragma unroll
      for (int ks = 0; ks < 4; ++ks){
        anxt[ks][0] = *(const f32x4*)(aptr + kc + 128 + ks * 32);
        anxt[ks][1] = *(const f32x4*)(aptr + kc + 128 + ks * 32 + 4);
      }
    }
    __syncthreads();

#pragma unroll
    for (int ks = 0; ks < 4; ++ks){
      short8 a;
#pragma unroll
      for (int q = 0; q < 4; ++q){
        a[q]     = (short)f2bf(acur[ks][0][q]);
        a[4 + q] = (short)f2bf(acur[ks][1][q]);
      }
#pragma unroll
      for (int nt = 0; nt < 4; ++nt){
        int n = wcol + nt * 16 + l16;
        int p = (ks * 4 + quad) ^ l16;
        short8 b = *(const short8*)(&Bt[n * 128 + p * 8]);
        acc[nt] = __builtin_amdgcn_mfma_f32_16x16x32_bf16(a, b, acc[nt], 0, 0, 0);
      }
    }
    __syncthreads();
  };

  for (int kc = 0; kc < K; kc += 256){
    chunk_step(afA, afB, kc);
    chunk_step(afB, afA, kc + 128);
  }

  // ---- epilogue: optional f32 P output ----
  if (outf){
#pragma unroll
    for (int nt = 0; nt < 4; ++nt){
      int col = wcol + nt * 16 + l16;
#pragma unroll
      for (int r = 0; r < 4; ++r){
        int mr = m0 + wrow + quad * 4 + r;
        if (mr < M) outf[(long)mr * D + col] = acc[nt][r];
      }
    }
  }

  // ---- epilogue: xw = bf16(P) @ Wx + rb for both layers ----
  // wave pair (w, w^2) shares row-tile (w&1): exchange col halves via LDS
  u16* Pl = Bt + (wave & 1) * 2176;   // [16][136] bf16, 272B rows (aligned)
#pragma unroll
  for (int nt = 0; nt < 4; ++nt)
#pragma unroll
    for (int r = 0; r < 4; ++r)
      Pl[(quad * 4 + r) * HP + wcol + nt * 16 + l16] = f2bf(acc[nt][r]);
  __syncthreads();

  short8 paf[4];
#pragma unroll
  for (int ks = 0; ks < 4; ++ks)
    paf[ks] = *(const short8*)(&Pl[l16 * HP + ks * 32 + quad * 8]);

  auto xw_pass = [&](const u16* Wx, const float* rb, float* xw){
    f32x4 ac2[4];
#pragma unroll
    for (int nt = 0; nt < 4; ++nt){
      float bv = rb[wcol + nt * 16 + l16];
      f32x4 tv = {bv, bv, bv, bv};
      ac2[nt] = tv;
    }
#pragma unroll
    for (int nt = 0; nt < 4; ++nt){
#pragma unroll
      for (int ks = 0; ks < 4; ++ks){
        short8 b = *(const short8*)(Wx + (wcol + nt * 16 + l16) * D + ks * 32 + quad * 8);
        ac2[nt] = __builtin_amdgcn_mfma_f32_16x16x32_bf16(paf[ks], b, ac2[nt], 0, 0, 0);
      }
    }
#pragma unroll
    for (int nt = 0; nt < 4; ++nt){
      int col = wcol + nt * 16 + l16;
#pragma unroll
      for (int r = 0; r < 4; ++r){
        int mr = m0 + (wave & 1) * 16 + quad * 4 + r;
        if (mr < M) xw[(long)mr * D + col] = ac2[nt][r];
      }
    }
  };
  xw_pass(Wx0, rb0, xw0);
  xw_pass(Wx1, rb1, xw1);
}

// xw for the cell type (table already 128-wide bf16): grid (32, 2)
__global__ __launch_bounds__(256) void xw_cell(
    const u16* __restrict__ cellT,  // bf16 [2000][128]
    const u16* __restrict__ WxT6,   // bf16 [6][128][128]
    const float* __restrict__ bvec, // f32 [6][128] (rnn_b)
    float* __restrict__ xwb)        // f32 [2][26000][128]
{
  int l = blockIdx.y;
  int mat = l * 3;                  // type 0 = cell
  const u16* WT = WxT6 + (size_t)mat * 16384;

  int lane = threadIdx.x & 63, wave = threadIdx.x >> 6;
  int quad = lane >> 4, l16 = lane & 15;
  int mt = blockIdx.x * 64 + wave * 16;
  int mr = min(mt + l16, 1999);

  short8 a[4];
#pragma unroll
  for (int ks = 0; ks < 4; ++ks)
    a[ks] = *(const short8*)(cellT + (long)mr * D + ks * 32 + quad * 8);

  f32x4 acc[8];
#pragma unroll
  for (int nt = 0; nt < 8; ++nt){
    float bv = bvec[mat * D + nt * 16 + l16];
    f32x4 tv = {bv, bv, bv, bv};
    acc[nt] = tv;
  }
#pragma unroll
  for (int nt = 0; nt < 8; ++nt){
#pragma unroll
    for (int ks = 0; ks < 4; ++ks){
      short8 b = *(const short8*)(WT + (nt * 16 + l16) * D + ks * 32 + quad * 8);
      acc[nt] = __builtin_amdgcn_mfma_f32_16x16x32_bf16(a[ks], b, acc[nt], 0, 0, 0);
    }
  }
#pragma unroll
  for (int nt = 0; nt < 8; ++nt){
    int col = nt * 16 + l16;
#pragma unroll
    for (int r = 0; r < 4; ++r){
      int mrow = mt + quad * 4 + r;
      if (mrow < 2000)
        xwb[((long)l * 26000 + mrow) * D + col] = acc[nt][r];
    }
  }
}

// Fused 6-way RNN (3 types x 2 layers): grid = (256, 3, 2), block 256 = 4 waves.
// h = tanh(xw_gathered + h @ Wh). Proven round-4/5 structure (HP=136 aligned).
__global__ __launch_bounds__(256, 3) void rnn6_kernel(
    const float* __restrict__ xwb,   // f32 [2][26000][128]
    const u16* __restrict__ WhT6,    // bf16 [6][128][128]
    const int* __restrict__ cn, const int* __restrict__ dn,
    const int* __restrict__ gn,      // [2][4096][10]
    u16* __restrict__ agg)           // bf16 [2][3][4096][128]
{
  __shared__ u16 hbuf[16 * HP];

  int t = blockIdx.y, l = blockIdx.z;
  const int* idx = (t == 0) ? cn : (t == 1) ? dn : gn;
  int rbase = (t == 0) ? 0 : (t == 1) ? 2000 : 6000;
  int nmax  = (t == 0) ? 2000 : (t == 1) ? 4000 : 20000;
  const float* xw = xwb + ((size_t)l * 26000 + rbase) * D;
  const u16* WT = WhT6 + (size_t)(l * 3 + t) * 16384;

  int tid = threadIdx.x, lane = tid & 63, wave = tid >> 6;
  int quad = lane >> 4, l16 = lane & 15;
  int n0 = wave * 32;

  short8 whf[2][4];
#pragma unroll
  for (int nt = 0; nt < 2; ++nt){
    int n = n0 + nt * 16 + l16;
#pragma unroll
    for (int ks = 0; ks < 4; ++ks)
      whf[nt][ks] = *(const short8*)(WT + n * D + ks * 32 + quad * 8);
  }

  for (int i = tid; i < 16 * HP; i += 256) hbuf[i] = 0;   // h0 = zeros

  int brow = blockIdx.x * 16;
  const int* ip = idx + ((size_t)l * NB + brow + quad * 4) * Ssz;
  long arow = ((long)(l * 3 + t) * NB + brow) * D;

  int nidA[4], nidB[4];
  float xwA[8], xwB[8];
#pragma unroll
  for (int r = 0; r < 4; ++r) nidA[r] = min(max(ip[r * Ssz], 0), nmax - 1);
#pragma unroll
  for (int r = 0; r < 4; ++r){
    const float* p = xw + (long)nidA[r] * D + n0 + l16;
    xwA[r] = p[0]; xwA[4 + r] = p[16];
  }
#pragma unroll
  for (int r = 0; r < 4; ++r) nidB[r] = min(max(ip[r * Ssz + 1], 0), nmax - 1);
  __syncthreads();   // hbuf zeros visible

  auto step = [&](int s, float (&xwc)[8], int (&nidn)[4],
                  float (&xwn)[8], int (&nidf)[4]){
    if (s + 1 < Ssz){
#pragma unroll
      for (int r = 0; r < 4; ++r){
        const float* p = xw + (long)nidn[r] * D + n0 + l16;
        xwn[r] = p[0]; xwn[4 + r] = p[16];
      }
    }
    if (s + 2 < Ssz){
#pragma unroll
      for (int r = 0; r < 4; ++r)
        nidf[r] = min(max(ip[r * Ssz + s + 2], 0), nmax - 1);
    }
    short8 hf[4];
#pragma unroll
    for (int ks = 0; ks < 4; ++ks)
      hf[ks] = *(const short8*)(&hbuf[l16 * HP + ks * 32 + quad * 8]);
    f32x4 acc0 = {xwc[0], xwc[1], xwc[2], xwc[3]};
    f32x4 acc1 = {xwc[4], xwc[5], xwc[6], xwc[7]};
#pragma unroll
    for (int ks = 0; ks < 4; ++ks){
      acc0 = __builtin_amdgcn_mfma_f32_16x16x32_bf16(hf[ks], whf[0][ks], acc0, 0, 0, 0);
      acc1 = __builtin_amdgcn_mfma_f32_16x16x32_bf16(hf[ks], whf[1][ks], acc1, 0, 0, 0);
    }
    __syncthreads();   // all waves done READING old h
#pragma unroll
    for (int r = 0; r < 4; ++r){
      float v0 = ftanh(acc0[r]);
      float v1 = ftanh(acc1[r]);
      hbuf[(quad * 4 + r) * HP + n0 + l16]      = f2bf(v0);
      hbuf[(quad * 4 + r) * HP + n0 + 16 + l16] = f2bf(v1);
      if (s == Ssz - 1){
        long o = arow + (long)(quad * 4 + r) * D;
        agg[o + n0 + l16]      = f2bf(v0);
        agg[o + n0 + 16 + l16] = f2bf(v1);
      }
    }
    __syncthreads();   // new h visible
  };

  step(0, xwA, nidB, xwB, nidA);
  step(1, xwB, nidA, xwA, nidB);
  step(2, xwA, nidB, xwB, nidA);
  step(3, xwB, nidA, xwA, nidB);
  step(4, xwA, nidB, xwB, nidA);
  step(5, xwB, nidA, xwA, nidB);
  step(6, xwA, nidB, xwB, nidA);
  step(7, xwB, nidA, xwA, nidB);
  step(8, xwA, nidB, xwB, nidA);
  step(9, xwB, nidA, xwA, nidB);
}

// Fused: h0 gather + both attention layers; h stays in registers between layers.
__global__ __launch_bounds__(256) void att2_kernel(
    const float* __restrict__ drugPf,  // f32 [4000][128]
    const int* __restrict__ center_ids,
    const u16* __restrict__ agg,       // bf16 [2][3][4096][128]
    const float* __restrict__ att_w,   // f32 [2][256]
    float* __restrict__ out)           // f32 [4096][128]
{
  int gt = blockIdx.x * 256 + threadIdx.x;
  int lane = gt & 63;
  int b = gt >> 6;
  int e = 2 * lane;

  int row = min(max(center_ids[b], 0), 3999);
  float h0 = drugPf[(long)row * D + e];
  float h1 = drugPf[(long)row * D + e + 1];

#pragma unroll
  for (int l = 0; l < 2; ++l){
    float c[4][2];
    c[0][0] = h0; c[0][1] = h1;
#pragma unroll
    for (int t = 0; t < 3; ++t){
      long o = ((long)(l * 3 + t) * NB + b) * D + e;
      c[t + 1][0] = bf2f(agg[o]);
      c[t + 1][1] = bf2f(agg[o + 1]);
    }
    const float* aw = att_w + l * 2 * D;
    float as0 = aw[e],     as1 = aw[e + 1];
    float ac0 = aw[D + e], ac1 = aw[D + e + 1];

    float selfp = c[0][0] * as0 + c[0][1] * as1;
    float sc[4];
#pragma unroll
    for (int cc = 0; cc < 4; ++cc) sc[cc] = selfp + c[cc][0] * ac0 + c[cc][1] * ac1;
#pragma unroll
    for (int off = 32; off >= 1; off >>= 1){
#pragma unroll
      for (int cc = 0; cc < 4; ++cc) sc[cc] += __shfl_xor(sc[cc], off, 64);
    }
#pragma unroll
    for (int cc = 0; cc < 4; ++cc) sc[cc] = sc[cc] > 0.f ? sc[cc] : 0.01f * sc[cc];

    float mx = fmaxf(fmaxf(sc[0], sc[1]), fmaxf(sc[2], sc[3]));
    float ex[4], ssum = 0.f;
#pragma unroll
    for (int cc = 0; cc < 4; ++cc){ ex[cc] = expf(sc[cc] - mx); ssum += ex[cc]; }
    float o0 = 0.f, o1 = 0.f;
#pragma unroll
    for (int cc = 0; cc < 4; ++cc){
      float a = ex[cc] / ssum;
      o0 += a * c[cc][0];
      o1 += a * c[cc][1];
    }
    h0 = o0; h1 = o1;
  }
  out[(long)b * D + e]     = h0;
  out[(long)b * D + e + 1] = h1;
}

extern "C" void kernel_launch(void* const* d_in, const int* in_sizes, int n_in,
                              void* d_out, int out_size, void* d_ws, size_t ws_size,
                              hipStream_t stream)
{
  const float* drug_feats = (const float*)d_in[0];   // [4000][1024]
  const float* gene_feats = (const float*)d_in[1];   // [20000][2048]
  const float* cell_tab   = (const float*)d_in[2];   // [2000][128]
  const float* W_drug     = (const float*)d_in[3];   // [1024][128]
  const float* b_drug     = (const float*)d_in[4];   // [128]
  const float* W_gene     = (const float*)d_in[5];   // [2048][128]
  const float* b_gene     = (const float*)d_in[6];   // [128]
  const float* rnn_Wx     = (const float*)d_in[7];   // [2][3][128][128]
  const float* rnn_Wh     = (const float*)d_in[8];
  const float* rnn_b      = (const float*)d_in[9];   // [2][3][128]
  const float* att_w      = (const float*)d_in[10];  // [2][256]
  const int* center_ids   = (const int*)d_in[11];    // [4096]
  const int* cell_neigh   = (const int*)d_in[12];    // [2][4096][10]
  const int* drug_neigh   = (const int*)d_in[13];
  const int* gene_neigh   = (const int*)d_in[14];

  // ws layout (u16 units):
  //  WdT 131072 | WgT 262144 | WxT6 98304 | WhT6 98304 | cellT 256000
  //  | drugPf f32 512000 | xwb f32 6656000 | agg 6*4096*128
  u16* ws     = (u16*)d_ws;
  u16* WdT    = ws;
  u16* WgT    = WdT + 131072;
  u16* WxT6   = WgT + 262144;
  u16* WhT6   = WxT6 + 98304;
  u16* cellT  = WhT6 + 98304;
  float* drugPf = (float*)(cellT + 256000);
  float* xwb    = drugPf + 512000;
  u16* agg      = (u16*)(xwb + 6656000);

  float* h = (float*)d_out;               // f32 [4096][128]

  // 1. preamble (one launch)
  prep_kernel<<<2804, 256, 0, stream>>>(W_drug, W_gene, rnn_Wx, rnn_Wh, cell_tab,
                                        WdT, WgT, WxT6, WhT6, cellT);

  // 2+3. dense table projections with fused x@Wx epilogues (32-row tiles)
  proj_gemm<<<125, 256, 0, stream>>>(drug_feats, 1024, 4000, WdT, b_drug,
                                     WxT6 + 1 * 16384, WxT6 + 4 * 16384,
                                     rnn_b + 1 * D,    rnn_b + 4 * D,
                                     xwb + (size_t)(0 * 26000 + 2000) * D,
                                     xwb + (size_t)(1 * 26000 + 2000) * D,
                                     drugPf);
  proj_gemm<<<625, 256, 0, stream>>>(gene_feats, 2048, 20000, WgT, b_gene,
                                     WxT6 + 2 * 16384, WxT6 + 5 * 16384,
                                     rnn_b + 2 * D,    rnn_b + 5 * D,
                                     xwb + (size_t)(0 * 26000 + 6000) * D,
                                     xwb + (size_t)(1 * 26000 + 6000) * D,
                                     (float*)nullptr);

  // 4. cell xw (tiny)
  xw_cell<<<dim3(32, 2), 256, 0, stream>>>(cellT, WxT6, rnn_b, xwb);

  // 5. all 6 (layer,type) RNN aggregations in one launch
  rnn6_kernel<<<dim3(NB / 16, 3, 2), 256, 0, stream>>>(
      xwb, WhT6, cell_neigh, drug_neigh, gene_neigh, agg);

  // 6. h0 gather + both attention layers fused
  att2_kernel<<<NB / 4, 256, 0, stream>>>(drugPf, center_ids, agg, att_w, h);
}